// Round 1
// baseline (11318.285 us; speedup 1.0000x reference)
//
#include <hip/hip_runtime.h>
#include <stdint.h>

#define BB 512
#define TT 256
#define FF 128
#define HH 256
#define NB 32          // blocks (16 rows each)
#define MR 16
#define EPSL 1e-9f

// ws bf16-element offsets. B-fragment-swizzled: [kt][nt][lane][8],
// elem (kt,nt,lane,j) holds B[k=kt*32+(lane>>4)*8+j][n=nt*16+(lane&15)]
#define E_WDH 0        // kt 4, nt 16  (gamma_h: K=128, N=256)
#define E_WH  32768    // kt 8, nt 8   (x_h:    K=256, N=128)
#define E_WF  65536    // kt 4, nt 8   (z_h:    K=128, N=128, diag zeroed)
#define E_WC  81920    // kt 8, nt 8   (alpha:  K=256, N=128)
#define E_W2  114688   // kt 16, nt 64 (gates:  K=512, N=1024)
#define E_END 638976
#define OFF_MSUM (E_END * 2)            // f32 [256]
#define OFF_PART (OFF_MSUM + 1024)      // f32 [3][TT][NB]

typedef __attribute__((ext_vector_type(8))) short s8v;   // 8 bf16
typedef __attribute__((ext_vector_type(4))) float f4v;   // 4 f32

__device__ __forceinline__ uint16_t f2bf(float v) {
    uint32_t u = __float_as_uint(v);
    return (uint16_t)((u + 0x7fffu + ((u >> 16) & 1u)) >> 16);  // RNE
}
__device__ __forceinline__ float fexp(float x) { return __expf(x); }
__device__ __forceinline__ float fsigm(float x) { return 1.f / (1.f + __expf(-x)); }
__device__ __forceinline__ float ftanh(float x) {
    float e = __expf(2.f * x);
    return 1.f - 2.f / (e + 1.f);
}
__device__ __forceinline__ uint2 pack4(float a, float b, float c, float d) {
    uint2 r;
    r.x = (uint32_t)f2bf(a) | ((uint32_t)f2bf(b) << 16);
    r.y = (uint32_t)f2bf(c) | ((uint32_t)f2bf(d) << 16);
    return r;
}
// A-swizzled LDS index for element (k, m): lane=(k>>3 &3)*16+m, chunk j=k&7
__device__ __forceinline__ int aidx(int k, int m) {
    return ((k >> 5) << 9) + (((((k >> 3) & 3) << 4) + m) << 3) + (k & 7);
}

// Barrier WITHOUT the compiler's vmcnt(0) drain: LDS ordering is all we need
// across phases; global weight prefetches stay in flight (m201 pattern).
__device__ __forceinline__ void block_sync() {
    asm volatile("s_waitcnt lgkmcnt(0)\n\ts_barrier" ::: "memory");
}

// ---------------- prep: pack weights into B-fragment bf16 layout ----------------
__global__ void prep_weights(const float* __restrict__ Wdh, const float* __restrict__ Wh,
                             const float* __restrict__ Wf, const float* __restrict__ Wc,
                             const float* __restrict__ Wih, const float* __restrict__ Whh,
                             uint16_t* __restrict__ wsu) {
    const int total = E_END;
    for (int i = blockIdx.x * blockDim.x + threadIdx.x; i < total; i += gridDim.x * blockDim.x) {
        float v;
        if (i < 32768) {                        // WdhB
            int o = i, j = o & 7, lane = (o >> 3) & 63, q = o >> 9;
            int nt = q & 15;  // kt = q>>4
            int k = (q >> 4) * 32 + (lane >> 4) * 8 + j;
            int n = nt * 16 + (lane & 15);
            v = Wdh[n * 128 + k];               // B[k][n] = Wdh[n][k]
        } else if (i < 65536) {                 // WhB
            int o = i - 32768, j = o & 7, lane = (o >> 3) & 63, q = o >> 9;
            int nt = q & 7;
            int k = (q >> 3) * 32 + (lane >> 4) * 8 + j;
            int n = nt * 16 + (lane & 15);
            v = Wh[n * 256 + k];
        } else if (i < 81920) {                 // WfB (diag masked)
            int o = i - 65536, j = o & 7, lane = (o >> 3) & 63, q = o >> 9;
            int nt = q & 7;
            int k = (q >> 3) * 32 + (lane >> 4) * 8 + j;
            int n = nt * 16 + (lane & 15);
            v = (k == n) ? 0.f : Wf[n * 128 + k];
        } else if (i < 114688) {                // WcB
            int o = i - 81920, j = o & 7, lane = (o >> 3) & 63, q = o >> 9;
            int nt = q & 7;
            int k = (q >> 3) * 32 + (lane >> 4) * 8 + j;
            int n = nt * 16 + (lane & 15);
            v = Wc[n * 256 + k];
        } else {                                // W2B
            int o = i - 114688, j = o & 7, lane = (o >> 3) & 63, q = o >> 9;
            int nt = q & 63;
            int k = (q >> 6) * 32 + (lane >> 4) * 8 + j;
            int g = nt * 16 + (lane & 15);
            v = (k < 256) ? Wih[g * 256 + k] : Whh[g * 256 + (k - 256)];
        }
        wsu[i] = f2bf(v);
    }
}

// ---------------- msum[t] ----------------
__global__ void msum_kernel(const float* __restrict__ mask, float* __restrict__ msum) {
    int t = blockIdx.x;
    float s = 0.f;
    for (int i = threadIdx.x; i < BB * FF; i += 256) {
        int b = i >> 7, f = i & 127;
        s += mask[((long)b * TT + t) * FF + f];
    }
    __shared__ float red[4];
    for (int off = 32; off; off >>= 1) s += __shfl_down(s, off);
    if ((threadIdx.x & 63) == 0) red[threadIdx.x >> 6] = s;
    __syncthreads();
    if (threadIdx.x == 0) msum[t] = red[0] + red[1] + red[2] + red[3];
}

// ---------------- main: 32 blocks x 512 threads (8 waves), 16 rows/block, MFMA ----------------
// Wave w owns h-columns [32w, 32w+32): G1 gamma_h tiles {2w,2w+1}, G4 gate tiles
// {g*16+2w, g*16+2w+1} for g=i,f,g,o. h and c persist in registers in C-fragment
// layout (lane (q,col): rows q*4+r, cols 32w+16p+col).
__launch_bounds__(512, 2)
__global__ void rits_main(const float* __restrict__ values, const float* __restrict__ mask,
                          const float* __restrict__ deltas,
                          const float* __restrict__ bdh, const float* __restrict__ Wdx,
                          const float* __restrict__ bdx, const float* __restrict__ bh,
                          const float* __restrict__ bf_, const float* __restrict__ bc_,
                          const float* __restrict__ bih, const float* __restrict__ bhh,
                          const uint16_t* __restrict__ wsu,
                          float* __restrict__ part, float* __restrict__ out_imp) {
    __shared__ __align__(16) uint16_t dA[4 * 512];     // d,  A-layout, K=128
    __shared__ __align__(16) uint16_t gxmA[8 * 512];   // [gx|m], K=256
    __shared__ __align__(16) uint16_t hA[8 * 512];     // decayed h, K=256
    __shared__ __align__(16) uint16_t xcA[4 * 512];    // x_c, K=128
    __shared__ __align__(16) uint16_t actA[16 * 512];  // [cc|m|h], K=512
    __shared__ __align__(16) float x32[16 * 132];
    __shared__ __align__(16) float m32[16 * 132];
    __shared__ float wred[3][8];

    const int tid = threadIdx.x;
    const int blk = blockIdx.x;
    const int r0 = blk * MR;
    const int w = tid >> 6;        // wave 0..7
    const int L = tid & 63;        // lane
    const int col = L & 15;
    const int q = L >> 4;

    const s8v* WDHB = (const s8v*)(wsu + E_WDH);
    const s8v* WHB  = (const s8v*)(wsu + E_WH);
    const s8v* WFB  = (const s8v*)(wsu + E_WF);
    const s8v* WCB  = (const s8v*)(wsu + E_WC);
    const s8v* W2B  = (const s8v*)(wsu + E_W2);

    // ---- hoisted per-thread constants ----
    const int rowi = tid >> 5;          // staging row
    const int f4 = (tid & 31) * 4;      // staging f base
    float cwdx[4], cbdx[4];
    #pragma unroll
    for (int e = 0; e < 4; ++e) {
        cwdx[e] = Wdx[(f4 + e) * FF + (f4 + e)];
        cbdx[e] = bdx[f4 + e];
    }
    const float bdh0 = bdh[32 * w + col];
    const float bdh1 = bdh[32 * w + 16 + col];
    const int fw = 16 * w + col;        // this wave's f column (N=128 stages)
    const float c_bh = bh[fw], c_bf = bf_[fw], c_bc = bc_[fw];
    float gbv[8];                       // gate bias, j = g*2+p for tile g*16+2w+p
    #pragma unroll
    for (int j = 0; j < 8; ++j) {
        int ntj = ((j >> 1) << 4) + 2 * w + (j & 1);
        int g = ntj * 16 + col;
        gbv[j] = bih[g] + bhh[g];
    }

    // persistent LSTM state in registers: index p*4+r -> (row q*4+r, col 32w+16p+col)
    float cst[8], hv[8];
    #pragma unroll
    for (int e = 0; e < 8; ++e) { cst[e] = 0.f; hv[e] = 0.f; }

    // ---- prologue: load + stage t=0 inputs ----
    float4 xv, mv, dv;
    {
        long base = ((long)(r0 + rowi) * TT + 0) * FF + f4;
        xv = *(const float4*)(values + base);
        mv = *(const float4*)(mask + base);
        dv = *(const float4*)(deltas + base);
    }
    uint2 pmv;
    {
        *(float4*)(x32 + rowi * 132 + f4) = xv;
        *(float4*)(m32 + rowi * 132 + f4) = mv;
        float g0 = fexp(-fmaxf(dv.x * cwdx[0] + cbdx[0], 0.f));
        float g1 = fexp(-fmaxf(dv.y * cwdx[1] + cbdx[1], 0.f));
        float g2 = fexp(-fmaxf(dv.z * cwdx[2] + cbdx[2], 0.f));
        float g3 = fexp(-fmaxf(dv.w * cwdx[3] + cbdx[3], 0.f));
        *(uint2*)(dA + aidx(f4, rowi)) = pack4(dv.x, dv.y, dv.z, dv.w);
        *(uint2*)(gxmA + aidx(f4, rowi)) = pack4(g0, g1, g2, g3);
        pmv = pack4(mv.x, mv.y, mv.z, mv.w);
        *(uint2*)(gxmA + aidx(128 + f4, rowi)) = pmv;
    }
    s8v bp[2][8];                       // G4 ping-pong b-fragment buffers
    block_sync();                       // S1 (t=0)

    #pragma unroll 1
    for (int t = 0; t < TT; ++t) {
        s8v bG1[8], bG2[8], bF4[4], bC8[8];
        // ================= G1: gamma_h GEMM + decay h (h from registers) =================
        #pragma unroll
        for (int kt = 0; kt < 4; ++kt) {
            bG1[kt]     = WDHB[(kt * 16 + 2 * w) * 64 + L];
            bG1[4 + kt] = WDHB[(kt * 16 + 2 * w + 1) * 64 + L];
        }
        #pragma unroll
        for (int kt = 0; kt < 8; ++kt) bG2[kt] = WHB[(kt * 8 + w) * 64 + L];  // prefetch for G2
        *(uint2*)(actA + aidx(128 + f4, rowi)) = pmv;   // m part of act (safe: actA reads ended at S5)
        {
            s8v ad[4];
            #pragma unroll
            for (int kt = 0; kt < 4; ++kt) ad[kt] = *(const s8v*)(dA + kt * 512 + L * 8);
            f4v ac0 = {0.f, 0.f, 0.f, 0.f}, ac1 = ac0;
            #pragma unroll
            for (int kt = 0; kt < 4; ++kt) {
                ac0 = __builtin_amdgcn_mfma_f32_16x16x32_bf16(ad[kt], bG1[kt], ac0, 0, 0, 0);
                ac1 = __builtin_amdgcn_mfma_f32_16x16x32_bf16(ad[kt], bG1[4 + kt], ac1, 0, 0, 0);
            }
            #pragma unroll
            for (int r = 0; r < 4; ++r) {
                int m = q * 4 + r;
                int n0 = 32 * w + col;
                float hd0 = hv[r] * fexp(-fmaxf(ac0[r] + bdh0, 0.f));
                uint16_t hb0 = f2bf(hd0);
                hA[aidx(n0, m)] = hb0;
                actA[aidx(256 + n0, m)] = hb0;
                int n1 = n0 + 16;
                float hd1 = hv[4 + r] * fexp(-fmaxf(ac1[r] + bdh1, 0.f));
                uint16_t hb1 = f2bf(hd1);
                hA[aidx(n1, m)] = hb1;
                actA[aidx(256 + n1, m)] = hb1;
            }
        }
        block_sync();  // S2

        // ================= G2: x_h GEMM, loss1, x_c =================
        #pragma unroll
        for (int kt = 0; kt < 4; ++kt) bF4[kt] = WFB[(kt * 8 + w) * 64 + L];  // prefetch for G3
        #pragma unroll
        for (int kt = 0; kt < 8; ++kt) bC8[kt] = WCB[(kt * 8 + w) * 64 + L];
        float xh[4], xr[4], mr[4], acc1 = 0.f;
        {
            s8v ah[8];
            #pragma unroll
            for (int kt = 0; kt < 8; ++kt) ah[kt] = *(const s8v*)(hA + kt * 512 + L * 8);
            f4v a = {0.f, 0.f, 0.f, 0.f};
            #pragma unroll
            for (int kt = 0; kt < 8; ++kt)
                a = __builtin_amdgcn_mfma_f32_16x16x32_bf16(ah[kt], bG2[kt], a, 0, 0, 0);
            #pragma unroll
            for (int r = 0; r < 4; ++r) {
                int m = q * 4 + r;
                xh[r] = a[r] + c_bh;
                xr[r] = x32[m * 132 + fw];
                mr[r] = m32[m * 132 + fw];
                acc1 += fabsf(xh[r] - xr[r]) * mr[r];
                float xc = mr[r] * xr[r] + (1.f - mr[r]) * xh[r];
                xcA[aidx(fw, m)] = f2bf(xc);
            }
        }
        block_sync();  // S3

        // ================= G3: z_h + alpha GEMMs, c_h, losses, c_c =================
        #pragma unroll
        for (int kk = 0; kk < 8; ++kk)                              // prefetch G4 tile j=0 lo
            bp[0][kk] = W2B[(kk * 64 + 2 * w) * 64 + L];
        {
            s8v axc[4];
            #pragma unroll
            for (int kt = 0; kt < 4; ++kt) axc[kt] = *(const s8v*)(xcA + kt * 512 + L * 8);
            s8v agm[8];
            #pragma unroll
            for (int kt = 0; kt < 8; ++kt) agm[kt] = *(const s8v*)(gxmA + kt * 512 + L * 8);
            f4v az = {0.f, 0.f, 0.f, 0.f}, aa = az;
            #pragma unroll
            for (int kt = 0; kt < 4; ++kt)
                az = __builtin_amdgcn_mfma_f32_16x16x32_bf16(axc[kt], bF4[kt], az, 0, 0, 0);
            #pragma unroll
            for (int kt = 0; kt < 8; ++kt)
                aa = __builtin_amdgcn_mfma_f32_16x16x32_bf16(agm[kt], bC8[kt], aa, 0, 0, 0);
            float acc2 = 0.f, acc3 = 0.f;
            #pragma unroll
            for (int r = 0; r < 4; ++r) {
                int m = q * 4 + r;
                float zh = az[r] + c_bf;
                float al = aa[r] + c_bc;
                float ch = al * zh + (1.f - al) * xh[r];
                acc2 += fabsf(zh - xr[r]) * mr[r];
                acc3 += fabsf(ch - xr[r]) * mr[r];
                float cc = mr[r] * xr[r] + (1.f - mr[r]) * ch;
                out_imp[((long)(r0 + m) * TT + t) * FF + fw] = cc;
                actA[aidx(fw, m)] = f2bf(cc);
            }
            float a1 = acc1, a2 = acc2, a3 = acc3;
            for (int off = 32; off; off >>= 1) {
                a1 += __shfl_down(a1, off);
                a2 += __shfl_down(a2, off);
                a3 += __shfl_down(a3, off);
            }
            if (L == 0) { wred[0][w] = a1; wred[1][w] = a2; wred[2][w] = a3; }
        }
        #pragma unroll
        for (int kk = 0; kk < 8; ++kk)                              // prefetch G4 tile j=0 hi
            bp[1][kk] = W2B[((8 + kk) * 64 + 2 * w) * 64 + L];
        block_sync();  // S4

        if (tid < 3) {
            float s = 0.f;
            #pragma unroll
            for (int e = 0; e < 8; ++e) s += wred[tid][e];
            part[((long)tid * TT + t) * NB + blk] = s;
        }

        // ================= G4: gates GEMM (K=512) pipelined + LSTM + stage t+1 =================
        {
            s8v aact[16];
            #pragma unroll
            for (int kt = 0; kt < 16; ++kt) aact[kt] = *(const s8v*)(actA + kt * 512 + L * 8);
            // prefetch next-step inputs (consumed at G4 tail, a whole phase away)
            const int tn = (t + 1 < TT) ? t + 1 : t;
            {
                long base = ((long)(r0 + rowi) * TT + tn) * FF + f4;
                xv = *(const float4*)(values + base);
                mv = *(const float4*)(mask + base);
                dv = *(const float4*)(deltas + base);
            }
            f4v accG[8];
            #pragma unroll
            for (int j = 0; j < 8; ++j) accG[j] = (f4v){0.f, 0.f, 0.f, 0.f};
            #pragma unroll
            for (int s = 0; s < 16; ++s) {           // half-tile slots: tile j=s>>1, half hf=s&1
                const int j = s >> 1, hf = s & 1;
                #pragma unroll
                for (int kk = 0; kk < 8; ++kk)
                    accG[j] = __builtin_amdgcn_mfma_f32_16x16x32_bf16(
                        aact[hf * 8 + kk], bp[s & 1][kk], accG[j], 0, 0, 0);
                if (s + 2 < 16) {                    // issue slot s+2 under the next slot's MFMAs
                    const int s2 = s + 2;
                    const int j2 = s2 >> 1, hf2 = s2 & 1;
                    const int nt2 = ((j2 >> 1) << 4) + 2 * w + (j2 & 1);
                    #pragma unroll
                    for (int kk = 0; kk < 8; ++kk)
                        bp[s & 1][kk] = W2B[((hf2 * 8 + kk) * 64 + nt2) * 64 + L];
                }
            }
            // LSTM pointwise in C-fragment layout (j = g*2+p)
            #pragma unroll
            for (int p = 0; p < 2; ++p) {
                #pragma unroll
                for (int r = 0; r < 4; ++r) {
                    float gi = accG[p][r]     + gbv[p];
                    float gf = accG[2 + p][r] + gbv[2 + p];
                    float gg = accG[4 + p][r] + gbv[4 + p];
                    float go = accG[6 + p][r] + gbv[6 + p];
                    float ct = fsigm(gf) * cst[p * 4 + r] + fsigm(gi) * ftanh(gg);
                    cst[p * 4 + r] = ct;
                    hv[p * 4 + r] = fsigm(go) * ftanh(ct);
                }
            }
            // stage inputs for t+1 (dA/gxmA/x32/m32 were last read before S4)
            *(float4*)(x32 + rowi * 132 + f4) = xv;
            *(float4*)(m32 + rowi * 132 + f4) = mv;
            float g0 = fexp(-fmaxf(dv.x * cwdx[0] + cbdx[0], 0.f));
            float g1 = fexp(-fmaxf(dv.y * cwdx[1] + cbdx[1], 0.f));
            float g2 = fexp(-fmaxf(dv.z * cwdx[2] + cbdx[2], 0.f));
            float g3 = fexp(-fmaxf(dv.w * cwdx[3] + cbdx[3], 0.f));
            *(uint2*)(dA + aidx(f4, rowi)) = pack4(dv.x, dv.y, dv.z, dv.w);
            *(uint2*)(gxmA + aidx(f4, rowi)) = pack4(g0, g1, g2, g3);
            pmv = pack4(mv.x, mv.y, mv.z, mv.w);
            *(uint2*)(gxmA + aidx(128 + f4, rowi)) = pmv;
        }
        block_sync();  // S5 == next step's S1 (orders actA reads vs next writes)
    }
}

// ---------------- finisher ----------------
__global__ void finisher(const float* __restrict__ part, const float* __restrict__ msum,
                         float* __restrict__ out2) {
    int t = threadIdx.x;
    float s1 = 0.f, s2 = 0.f, s3 = 0.f;
    const float* p1 = part + ((long)0 * TT + t) * NB;
    const float* p2 = part + ((long)1 * TT + t) * NB;
    const float* p3 = part + ((long)2 * TT + t) * NB;
    for (int b = 0; b < NB; ++b) { s1 += p1[b]; s2 += p2[b]; s3 += p3[b]; }
    float den = msum[t] + EPSL;
    float l12 = (s1 + s2) / den;
    float l3 = s3 / den;
    float xl = l12 + (float)(TT - t) * l3;
    float ml = l3;
    __shared__ float r1[4], r2[4];
    for (int off = 32; off; off >>= 1) {
        xl += __shfl_down(xl, off);
        ml += __shfl_down(ml, off);
    }
    if ((t & 63) == 0) { r1[t >> 6] = xl; r2[t >> 6] = ml; }
    __syncthreads();
    if (t == 0) {
        float X = r1[0] + r1[1] + r1[2] + r1[3];
        float M = r2[0] + r2[1] + r2[2] + r2[3];
        out2[0] = X / (float)(TT * 3);
        out2[1] = M / (float)TT;
    }
}

extern "C" void kernel_launch(void* const* d_in, const int* in_sizes, int n_in,
                              void* d_out, int out_size, void* d_ws, size_t ws_size,
                              hipStream_t stream) {
    const float* values = (const float*)d_in[0];
    const float* mask   = (const float*)d_in[1];
    const float* deltas = (const float*)d_in[2];
    const float* Wdh = (const float*)d_in[3];
    const float* bdh = (const float*)d_in[4];
    const float* Wdx = (const float*)d_in[5];
    const float* bdx = (const float*)d_in[6];
    const float* Wh  = (const float*)d_in[7];
    const float* bh  = (const float*)d_in[8];
    const float* Wf  = (const float*)d_in[9];
    const float* bf_ = (const float*)d_in[10];
    const float* Wc  = (const float*)d_in[11];
    const float* bc_ = (const float*)d_in[12];
    const float* Wih = (const float*)d_in[13];
    const float* Whh = (const float*)d_in[14];
    const float* bih = (const float*)d_in[15];
    const float* bhh = (const float*)d_in[16];

    float* out = (float*)d_out;
    uint16_t* wsu = (uint16_t*)d_ws;
    float* msum = (float*)((char*)d_ws + OFF_MSUM);
    float* part = (float*)((char*)d_ws + OFF_PART);

    prep_weights<<<2496, 256, 0, stream>>>(Wdh, Wh, Wf, Wc, Wih, Whh, wsu);
    msum_kernel<<<TT, 256, 0, stream>>>(mask, msum);
    rits_main<<<NB, 512, 0, stream>>>(values, mask, deltas, bdh, Wdx, bdx,
                                      bh, bf_, bc_, bih, bhh, wsu, part, out);
    finisher<<<1, 256, 0, stream>>>(part, msum, out + (long)BB * TT * FF);
}

// Round 2
// 9472.436 us; speedup vs baseline: 1.1949x; 1.1949x over previous
//
#include <hip/hip_runtime.h>
#include <stdint.h>

#define BB 512
#define TT 256
#define FF 128
#define HH 256
#define NB 32          // blocks (16 rows each)
#define MR 16
#define EPSL 1e-9f

// ws bf16-element offsets. B-fragment-swizzled: [kt][nt][lane][8],
// elem (kt,nt,lane,j) holds B[k=kt*32+(lane>>4)*8+j][n=nt*16+(lane&15)]
#define E_WDH 0        // kt 4, nt 16  (gamma_h: K=128, N=256)
#define E_WH  32768    // kt 8, nt 8   (x_h:    K=256, N=128)
#define E_WF  65536    // kt 4, nt 8   (z_h:    K=128, N=128, diag zeroed)
#define E_WC  81920    // kt 8, nt 8   (alpha:  K=256, N=128)
#define E_W2  114688   // kt 16, nt 64 (gates:  K=512, N=1024)
#define E_END 638976
#define OFF_MSUM (E_END * 2)            // f32 [256]
#define OFF_PART (OFF_MSUM + 1024)      // f32 [3][TT][NB]

// weight-fragment ring: 156 fragments/wave/step streamed via global_load_lds
#define TOTF 156
#define LEAD 8
#define RSLOTS 12      // 156 % 12 == 0 -> slot index is continuous across steps

typedef __attribute__((ext_vector_type(8))) short s8v;   // 8 bf16
typedef __attribute__((ext_vector_type(4))) float f4v;   // 4 f32

__device__ __forceinline__ uint16_t f2bf(float v) {
    uint32_t u = __float_as_uint(v);
    return (uint16_t)((u + 0x7fffu + ((u >> 16) & 1u)) >> 16);  // RNE
}
__device__ __forceinline__ float fexp(float x) { return __expf(x); }
__device__ __forceinline__ float fsigm(float x) { return 1.f / (1.f + __expf(-x)); }
__device__ __forceinline__ float ftanh(float x) {
    float e = __expf(2.f * x);
    return 1.f - 2.f / (e + 1.f);
}
__device__ __forceinline__ uint2 pack4(float a, float b, float c, float d) {
    uint2 r;
    r.x = (uint32_t)f2bf(a) | ((uint32_t)f2bf(b) << 16);
    r.y = (uint32_t)f2bf(c) | ((uint32_t)f2bf(d) << 16);
    return r;
}
// A-swizzled LDS index for element (k, m): lane=(k>>3 &3)*16+m, chunk j=k&7
__device__ __forceinline__ int aidx(int k, int m) {
    return ((k >> 5) << 9) + (((((k >> 3) & 3) << 4) + m) << 3) + (k & 7);
}

// Barrier WITHOUT vmcnt drain: LDS ordering only; ring DMAs stay in flight.
__device__ __forceinline__ void block_sync() {
    asm volatile("s_waitcnt lgkmcnt(0)\n\ts_barrier" ::: "memory");
}

// fragment f (0..155) -> bf16-element offset of its 1KB B-fragment for wave w
__device__ __forceinline__ int fragOff(int f, int w) {
    if (f < 8)  return E_WDH + ((f >> 1) * 16 + 2 * w + (f & 1)) * 512;   // G1
    if (f < 16) return E_WH + ((f - 8) * 8 + w) * 512;                    // G2
    if (f < 20) return E_WF + ((f - 16) * 8 + w) * 512;                   // G3 z_h
    if (f < 28) return E_WC + ((f - 20) * 8 + w) * 512;                   // G3 alpha
    int u = f - 28, s = u >> 4, kt = u & 15;                              // G4
    int p = s >> 2, g = s & 3;                                            // tile order p-major
    return E_W2 + (kt * 64 + g * 16 + 2 * w + p) * 512;
}

typedef __attribute__((address_space(1))) const void gas_t;
typedef __attribute__((address_space(3))) void las_t;

__device__ __forceinline__ void ring_issue(const uint16_t* wsu, uint16_t* ringw,
                                           int f, int w, int L) {
    const uint16_t* src = wsu + fragOff(f, w) + L * 8;          // per-lane 16B
    uint16_t* dst = ringw + (f % RSLOTS) * 512;                 // wave-uniform
    __builtin_amdgcn_global_load_lds((gas_t*)(const void*)src,
                                     (las_t*)(void*)dst, 16, 0, 0);
}

// wait so fragment f's DMA has landed (LEAD-1 issued after it; in-order retire)
#define VMW asm volatile("s_waitcnt vmcnt(7)" ::: "memory")
// consume fragment f: wait, ds_read, then issue f+LEAD (issue AFTER wait so a
// compiler-sunk issue can never make vmcnt(7) pass with f unretired)
#define RC(f, bvar)                                                              \
    VMW;                                                                         \
    s8v bvar = *(const s8v*)(ringw + ((f) % RSLOTS) * 512 + L * 8);              \
    ring_issue(wsu, ringw, ((f) + LEAD) % TOTF, w, L)

// ---------------- prep: pack weights into B-fragment bf16 layout ----------------
__global__ void prep_weights(const float* __restrict__ Wdh, const float* __restrict__ Wh,
                             const float* __restrict__ Wf, const float* __restrict__ Wc,
                             const float* __restrict__ Wih, const float* __restrict__ Whh,
                             uint16_t* __restrict__ wsu) {
    const int total = E_END;
    for (int i = blockIdx.x * blockDim.x + threadIdx.x; i < total; i += gridDim.x * blockDim.x) {
        float v;
        if (i < 32768) {                        // WdhB
            int o = i, j = o & 7, lane = (o >> 3) & 63, q = o >> 9;
            int nt = q & 15;  // kt = q>>4
            int k = (q >> 4) * 32 + (lane >> 4) * 8 + j;
            int n = nt * 16 + (lane & 15);
            v = Wdh[n * 128 + k];               // B[k][n] = Wdh[n][k]
        } else if (i < 65536) {                 // WhB
            int o = i - 32768, j = o & 7, lane = (o >> 3) & 63, q = o >> 9;
            int nt = q & 7;
            int k = (q >> 3) * 32 + (lane >> 4) * 8 + j;
            int n = nt * 16 + (lane & 15);
            v = Wh[n * 256 + k];
        } else if (i < 81920) {                 // WfB (diag masked)
            int o = i - 65536, j = o & 7, lane = (o >> 3) & 63, q = o >> 9;
            int nt = q & 7;
            int k = (q >> 3) * 32 + (lane >> 4) * 8 + j;
            int n = nt * 16 + (lane & 15);
            v = (k == n) ? 0.f : Wf[n * 128 + k];
        } else if (i < 114688) {                // WcB
            int o = i - 81920, j = o & 7, lane = (o >> 3) & 63, q = o >> 9;
            int nt = q & 7;
            int k = (q >> 3) * 32 + (lane >> 4) * 8 + j;
            int n = nt * 16 + (lane & 15);
            v = Wc[n * 256 + k];
        } else {                                // W2B
            int o = i - 114688, j = o & 7, lane = (o >> 3) & 63, q = o >> 9;
            int nt = q & 63;
            int k = (q >> 6) * 32 + (lane >> 4) * 8 + j;
            int g = nt * 16 + (lane & 15);
            v = (k < 256) ? Wih[g * 256 + k] : Whh[g * 256 + (k - 256)];
        }
        wsu[i] = f2bf(v);
    }
}

// ---------------- msum[t] ----------------
__global__ void msum_kernel(const float* __restrict__ mask, float* __restrict__ msum) {
    int t = blockIdx.x;
    float s = 0.f;
    for (int i = threadIdx.x; i < BB * FF; i += 256) {
        int b = i >> 7, f = i & 127;
        s += mask[((long)b * TT + t) * FF + f];
    }
    __shared__ float red[4];
    for (int off = 32; off; off >>= 1) s += __shfl_down(s, off);
    if ((threadIdx.x & 63) == 0) red[threadIdx.x >> 6] = s;
    __syncthreads();
    if (threadIdx.x == 0) msum[t] = red[0] + red[1] + red[2] + red[3];
}

// ---------------- main: 32 blocks x 512 threads (8 waves), 16 rows/block ----------------
// Wave w owns h-columns [32w,32w+32). Weight fragments stream through a
// wave-private 12-slot LDS ring (global_load_lds, 8 in flight, vmcnt(7) waits,
// in flight across the lgkm-only barriers). LSTM h/c state lives in registers.
__launch_bounds__(512, 2)
__global__ void rits_main(const float* __restrict__ values, const float* __restrict__ mask,
                          const float* __restrict__ deltas,
                          const float* __restrict__ bdh, const float* __restrict__ Wdx,
                          const float* __restrict__ bdx, const float* __restrict__ bh,
                          const float* __restrict__ bf_, const float* __restrict__ bc_,
                          const float* __restrict__ bih, const float* __restrict__ bhh,
                          const uint16_t* __restrict__ wsu,
                          float* __restrict__ part, float* __restrict__ out_imp) {
    __shared__ __align__(16) uint16_t ringS[8 * RSLOTS * 512];  // 96 KB weight ring
    __shared__ __align__(16) uint16_t dA[4 * 512];     // d,  A-layout, K=128
    __shared__ __align__(16) uint16_t gxmA[8 * 512];   // [gx|m], K=256
    __shared__ __align__(16) uint16_t hA[8 * 512];     // decayed h, K=256
    __shared__ __align__(16) uint16_t xcA[4 * 512];    // x_c, K=128
    __shared__ __align__(16) uint16_t ccA[4 * 512];    // c_c, K=128
    __shared__ __align__(16) float x32[16 * 132];
    __shared__ __align__(16) float m32[16 * 132];
    __shared__ float wred[3][8];

    const int tid = threadIdx.x;
    const int blk = blockIdx.x;
    const int r0 = blk * MR;
    const int w = tid >> 6;        // wave 0..7
    const int L = tid & 63;        // lane
    const int col = L & 15;
    const int q = L >> 4;
    uint16_t* ringw = ringS + w * RSLOTS * 512;

    // ---- hoisted per-thread constants ----
    const int rowi = tid >> 5;          // staging row
    const int f4 = (tid & 31) * 4;      // staging f base
    float cwdx[4], cbdx[4];
    #pragma unroll
    for (int e = 0; e < 4; ++e) {
        cwdx[e] = Wdx[(f4 + e) * FF + (f4 + e)];
        cbdx[e] = bdx[f4 + e];
    }
    const float bdh0 = bdh[32 * w + col];
    const float bdh1 = bdh[32 * w + 16 + col];
    const int fw = 16 * w + col;        // this wave's f column (N=128 stages)
    const float c_bh = bh[fw], c_bf = bf_[fw], c_bc = bc_[fw];
    float gbv[8];                       // gate bias, idx s=p*4+g for tile g*16+2w+p
    #pragma unroll
    for (int s = 0; s < 8; ++s) {
        int p = s >> 2, g = s & 3;
        int gi = (g * 16 + 2 * w + p) * 16 + col;
        gbv[s] = bih[gi] + bhh[gi];
    }

    // persistent LSTM state: idx p*4+r -> (row q*4+r, col 32w+16p+col)
    float cst[8], hv[8];
    #pragma unroll
    for (int e = 0; e < 8; ++e) { cst[e] = 0.f; hv[e] = 0.f; }

    // ---- prologue: load + stage t=0 inputs; prime the ring ----
    float4 xv, mv, dv;
    {
        long base = ((long)(r0 + rowi) * TT + 0) * FF + f4;
        xv = *(const float4*)(values + base);
        mv = *(const float4*)(mask + base);
        dv = *(const float4*)(deltas + base);
    }
    uint2 pmv;
    {
        *(float4*)(x32 + rowi * 132 + f4) = xv;
        *(float4*)(m32 + rowi * 132 + f4) = mv;
        float g0 = fexp(-fmaxf(dv.x * cwdx[0] + cbdx[0], 0.f));
        float g1 = fexp(-fmaxf(dv.y * cwdx[1] + cbdx[1], 0.f));
        float g2 = fexp(-fmaxf(dv.z * cwdx[2] + cbdx[2], 0.f));
        float g3 = fexp(-fmaxf(dv.w * cwdx[3] + cbdx[3], 0.f));
        *(uint2*)(dA + aidx(f4, rowi)) = pack4(dv.x, dv.y, dv.z, dv.w);
        *(uint2*)(gxmA + aidx(f4, rowi)) = pack4(g0, g1, g2, g3);
        pmv = pack4(mv.x, mv.y, mv.z, mv.w);
        *(uint2*)(gxmA + aidx(128 + f4, rowi)) = pmv;
    }
    #pragma unroll
    for (int f = 0; f < LEAD; ++f) ring_issue(wsu, ringw, f, w, L);
    block_sync();                       // S1 (t=0)

    #pragma unroll 1
    for (int t = 0; t < TT; ++t) {
        // ================= G1: gamma_h GEMM + decay h (h in registers) =================
        {
            s8v ad[4];
            #pragma unroll
            for (int kt = 0; kt < 4; ++kt) ad[kt] = *(const s8v*)(dA + kt * 512 + L * 8);
            f4v ac0 = {0.f, 0.f, 0.f, 0.f}, ac1 = ac0;
            #pragma unroll
            for (int kt = 0; kt < 4; ++kt) {
                { RC(kt * 2 + 0, b0);
                  ac0 = __builtin_amdgcn_mfma_f32_16x16x32_bf16(ad[kt], b0, ac0, 0, 0, 0); }
                { RC(kt * 2 + 1, b1);
                  ac1 = __builtin_amdgcn_mfma_f32_16x16x32_bf16(ad[kt], b1, ac1, 0, 0, 0); }
            }
            #pragma unroll
            for (int r = 0; r < 4; ++r) {
                int m = q * 4 + r;
                int n0 = 32 * w + col;
                float hd0 = hv[r] * fexp(-fmaxf(ac0[r] + bdh0, 0.f));
                hA[aidx(n0, m)] = f2bf(hd0);
                int n1 = n0 + 16;
                float hd1 = hv[4 + r] * fexp(-fmaxf(ac1[r] + bdh1, 0.f));
                hA[aidx(n1, m)] = f2bf(hd1);
            }
        }
        block_sync();  // S2

        // ================= G2: x_h GEMM, loss1, x_c =================
        float xh[4], xr[4], mr[4], acc1 = 0.f;
        {
            s8v ah[8];
            #pragma unroll
            for (int kt = 0; kt < 8; ++kt) ah[kt] = *(const s8v*)(hA + kt * 512 + L * 8);
            f4v a = {0.f, 0.f, 0.f, 0.f};
            #pragma unroll
            for (int kt = 0; kt < 8; ++kt) {
                RC(8 + kt, b);
                a = __builtin_amdgcn_mfma_f32_16x16x32_bf16(ah[kt], b, a, 0, 0, 0);
            }
            #pragma unroll
            for (int r = 0; r < 4; ++r) {
                int m = q * 4 + r;
                xh[r] = a[r] + c_bh;
                xr[r] = x32[m * 132 + fw];
                mr[r] = m32[m * 132 + fw];
                acc1 += fabsf(xh[r] - xr[r]) * mr[r];
                float xc = mr[r] * xr[r] + (1.f - mr[r]) * xh[r];
                xcA[aidx(fw, m)] = f2bf(xc);
            }
        }
        block_sync();  // S3

        // ================= G3: z_h + alpha GEMMs, c_h, losses, c_c =================
        s8v agm[8];                               // agm[4..7] reused as G4 A kt4-7 (m)
        {
            // prefetch next-step inputs early (consumed at G4 tail)
            const int tn = (t + 1 < TT) ? t + 1 : t;
            long base = ((long)(r0 + rowi) * TT + tn) * FF + f4;
            xv = *(const float4*)(values + base);
            mv = *(const float4*)(mask + base);
            dv = *(const float4*)(deltas + base);
            __builtin_amdgcn_sched_barrier(0);    // pin the loads here (no sinking)
        }
        {
            s8v axc[4];
            #pragma unroll
            for (int kt = 0; kt < 4; ++kt) axc[kt] = *(const s8v*)(xcA + kt * 512 + L * 8);
            #pragma unroll
            for (int kt = 0; kt < 8; ++kt) agm[kt] = *(const s8v*)(gxmA + kt * 512 + L * 8);
            f4v az = {0.f, 0.f, 0.f, 0.f}, aa = az;
            #pragma unroll
            for (int kt = 0; kt < 4; ++kt) {
                RC(16 + kt, b);
                az = __builtin_amdgcn_mfma_f32_16x16x32_bf16(axc[kt], b, az, 0, 0, 0);
            }
            #pragma unroll
            for (int kt = 0; kt < 8; ++kt) {
                RC(20 + kt, b);
                aa = __builtin_amdgcn_mfma_f32_16x16x32_bf16(agm[kt], b, aa, 0, 0, 0);
            }
            float acc2 = 0.f, acc3 = 0.f;
            #pragma unroll
            for (int r = 0; r < 4; ++r) {
                int m = q * 4 + r;
                float zh = az[r] + c_bf;
                float al = aa[r] + c_bc;
                float ch = al * zh + (1.f - al) * xh[r];
                acc2 += fabsf(zh - xr[r]) * mr[r];
                acc3 += fabsf(ch - xr[r]) * mr[r];
                float cc = mr[r] * xr[r] + (1.f - mr[r]) * ch;
                out_imp[((long)(r0 + m) * TT + t) * FF + fw] = cc;
                ccA[aidx(fw, m)] = f2bf(cc);
            }
            float a1 = acc1, a2 = acc2, a3 = acc3;
            for (int off = 32; off; off >>= 1) {
                a1 += __shfl_down(a1, off);
                a2 += __shfl_down(a2, off);
                a3 += __shfl_down(a3, off);
            }
            if (L == 0) { wred[0][w] = a1; wred[1][w] = a2; wred[2][w] = a3; }
        }
        block_sync();  // S4

        if (tid < 3) {
            float s = 0.f;
            #pragma unroll
            for (int e = 0; e < 8; ++e) s += wred[tid][e];
            part[((long)tid * TT + t) * NB + blk] = s;
        }

        // ================= G4: gates GEMM (K=512) via ring + LSTM + stage t+1 =====
        {
            s8v ccf[4], hf[8];                    // A kt0-3 (c_c), kt8-15 (h)
            #pragma unroll
            for (int kt = 0; kt < 4; ++kt) ccf[kt] = *(const s8v*)(ccA + kt * 512 + L * 8);
            #pragma unroll
            for (int kt = 0; kt < 8; ++kt) hf[kt] = *(const s8v*)(hA + kt * 512 + L * 8);
            #define AACT(kt) ((kt) < 4 ? ccf[kt] : ((kt) < 8 ? agm[kt] : hf[(kt) - 8]))
            #pragma unroll
            for (int p = 0; p < 2; ++p) {         // column half: cols 32w+16p+col
                f4v gacc[4];
                #pragma unroll
                for (int g = 0; g < 4; ++g) {     // gate i,f,g,o  (tile g*16+2w+p)
                    f4v acc = {0.f, 0.f, 0.f, 0.f};
                    #pragma unroll
                    for (int kt = 0; kt < 16; ++kt) {
                        const int f = 28 + (p * 4 + g) * 16 + kt;
                        RC(f, b);
                        acc = __builtin_amdgcn_mfma_f32_16x16x32_bf16(AACT(kt), b, acc, 0, 0, 0);
                    }
                    gacc[g] = acc;
                }
                #pragma unroll
                for (int r = 0; r < 4; ++r) {     // LSTM pointwise for this half
                    float gi = gacc[0][r] + gbv[p * 4 + 0];
                    float gf = gacc[1][r] + gbv[p * 4 + 1];
                    float gg = gacc[2][r] + gbv[p * 4 + 2];
                    float go = gacc[3][r] + gbv[p * 4 + 3];
                    float ct = fsigm(gf) * cst[p * 4 + r] + fsigm(gi) * ftanh(gg);
                    cst[p * 4 + r] = ct;
                    hv[p * 4 + r] = fsigm(go) * ftanh(ct);
                }
            }
            #undef AACT
            // stage inputs for t+1 (x32/m32/dA/gxmA last read before S4)
            *(float4*)(x32 + rowi * 132 + f4) = xv;
            *(float4*)(m32 + rowi * 132 + f4) = mv;
            float g0 = fexp(-fmaxf(dv.x * cwdx[0] + cbdx[0], 0.f));
            float g1 = fexp(-fmaxf(dv.y * cwdx[1] + cbdx[1], 0.f));
            float g2 = fexp(-fmaxf(dv.z * cwdx[2] + cbdx[2], 0.f));
            float g3 = fexp(-fmaxf(dv.w * cwdx[3] + cbdx[3], 0.f));
            *(uint2*)(dA + aidx(f4, rowi)) = pack4(dv.x, dv.y, dv.z, dv.w);
            *(uint2*)(gxmA + aidx(f4, rowi)) = pack4(g0, g1, g2, g3);
            pmv = pack4(mv.x, mv.y, mv.z, mv.w);
            *(uint2*)(gxmA + aidx(128 + f4, rowi)) = pmv;
        }
        block_sync();  // S5 == next step's S1
    }
}

// ---------------- finisher ----------------
__global__ void finisher(const float* __restrict__ part, const float* __restrict__ msum,
                         float* __restrict__ out2) {
    int t = threadIdx.x;
    float s1 = 0.f, s2 = 0.f, s3 = 0.f;
    const float* p1 = part + ((long)0 * TT + t) * NB;
    const float* p2 = part + ((long)1 * TT + t) * NB;
    const float* p3 = part + ((long)2 * TT + t) * NB;
    for (int b = 0; b < NB; ++b) { s1 += p1[b]; s2 += p2[b]; s3 += p3[b]; }
    float den = msum[t] + EPSL;
    float l12 = (s1 + s2) / den;
    float l3 = s3 / den;
    float xl = l12 + (float)(TT - t) * l3;
    float ml = l3;
    __shared__ float r1[4], r2[4];
    for (int off = 32; off; off >>= 1) {
        xl += __shfl_down(xl, off);
        ml += __shfl_down(ml, off);
    }
    if ((t & 63) == 0) { r1[t >> 6] = xl; r2[t >> 6] = ml; }
    __syncthreads();
    if (t == 0) {
        float X = r1[0] + r1[1] + r1[2] + r1[3];
        float M = r2[0] + r2[1] + r2[2] + r2[3];
        out2[0] = X / (float)(TT * 3);
        out2[1] = M / (float)TT;
    }
}

extern "C" void kernel_launch(void* const* d_in, const int* in_sizes, int n_in,
                              void* d_out, int out_size, void* d_ws, size_t ws_size,
                              hipStream_t stream) {
    const float* values = (const float*)d_in[0];
    const float* mask   = (const float*)d_in[1];
    const float* deltas = (const float*)d_in[2];
    const float* Wdh = (const float*)d_in[3];
    const float* bdh = (const float*)d_in[4];
    const float* Wdx = (const float*)d_in[5];
    const float* bdx = (const float*)d_in[6];
    const float* Wh  = (const float*)d_in[7];
    const float* bh  = (const float*)d_in[8];
    const float* Wf  = (const float*)d_in[9];
    const float* bf_ = (const float*)d_in[10];
    const float* Wc  = (const float*)d_in[11];
    const float* bc_ = (const float*)d_in[12];
    const float* Wih = (const float*)d_in[13];
    const float* Whh = (const float*)d_in[14];
    const float* bih = (const float*)d_in[15];
    const float* bhh = (const float*)d_in[16];

    float* out = (float*)d_out;
    uint16_t* wsu = (uint16_t*)d_ws;
    float* msum = (float*)((char*)d_ws + OFF_MSUM);
    float* part = (float*)((char*)d_ws + OFF_PART);

    prep_weights<<<2496, 256, 0, stream>>>(Wdh, Wh, Wf, Wc, Wih, Whh, wsu);
    msum_kernel<<<TT, 256, 0, stream>>>(mask, msum);
    rits_main<<<NB, 512, 0, stream>>>(values, mask, deltas, bdh, Wdx, bdx,
                                      bh, bf_, bc_, bih, bhh, wsu, part, out);
    finisher<<<1, 256, 0, stream>>>(part, msum, out + (long)BB * TT * FF);
}